// Round 1
// baseline (750.796 us; speedup 1.0000x reference)
//
#include <hip/hip_runtime.h>

typedef __attribute__((ext_vector_type(4))) float f32x4;
typedef __attribute__((ext_vector_type(8))) __bf16 bf16x8;

__device__ __forceinline__ unsigned short f2bf(float f) {
    return __builtin_bit_cast(unsigned short, (__bf16)f);
}

__device__ __forceinline__ void gload16(const void* g, void* l) {
    __builtin_amdgcn_global_load_lds(
        (const __attribute__((address_space(1))) void*)g,
        (__attribute__((address_space(3))) void*)l, 16, 0, 0);
}

// ---------------- convert x (f32 -> bf16, zero-pad rows to Mpad) ----------------
__global__ __launch_bounds__(256) void k_cvt_x(const float* __restrict__ x,
                                               unsigned short* __restrict__ xb,
                                               long total, long totalPad) {
    long i = ((long)blockIdx.x * 256 + threadIdx.x) * 4;
    if (i >= totalPad) return;
    if (i < total) {  // total is a multiple of 4
        float4 v = *(const float4*)(x + i);
        ushort4 u;
        u.x = f2bf(v.x); u.y = f2bf(v.y); u.z = f2bf(v.z); u.w = f2bf(v.w);
        *(ushort4*)(xb + i) = u;
    } else {
        ushort4 u = {0, 0, 0, 0};
        *(ushort4*)(xb + i) = u;
    }
}

// ---------------- build WT = [Wg|Wh|Wl]^T as bf16, 768 x 256 (n-major) ----------------
__global__ __launch_bounds__(256) void k_wt(const float* __restrict__ Wg,
                                            const float* __restrict__ Wh,
                                            const float* __restrict__ Wl,
                                            unsigned short* __restrict__ wt) {
    int t = blockIdx.x * 256 + threadIdx.x;   // 0 .. 768*256-1,  t = nn*256 + k
    int nn = t >> 8, k = t & 255;
    const float* W = (nn < 256) ? Wg : (nn < 512) ? Wh : Wl;
    int c = nn & 255;
    wt[t] = f2bf(W[k * 256 + c]);
}

// ---------------- fused GEMM: C(Mpad x 768) = Xbf16 @ [Wg|Wh|Wl] ----------------
// epilogue: cols 0-255 -> xs ; 256-511 -> h=relu(+bh) ; 512-767 -> xl=+bl
__global__ __launch_bounds__(256) void k_gemm(
    const unsigned short* __restrict__ A,   // Mpad x 256 bf16
    const unsigned short* __restrict__ BT,  // 768 x 256 bf16 (row n, col k)
    float* __restrict__ xs, float* __restrict__ hb, float* __restrict__ xlb,
    const float* __restrict__ bh, const float* __restrict__ bl, int M) {
    __shared__ unsigned short Al[128 * 32];
    __shared__ unsigned short Bl[128 * 32];
    const int tid = threadIdx.x;
    const int lane = tid & 63;
    const int wave = tid >> 6;
    const int tm = blockIdx.x, tn = blockIdx.y;
    const int wm = (wave >> 1) * 64, wn = (wave & 1) * 64;

    f32x4 acc[4][4] = {};

    // staging: thread t owns LDS bytes [t*16, t*16+16) (+4096 for sweep 1)
    const int r0 = tid >> 2;            // row within 64-row sweep
    const int ce = (tid & 3) * 8;       // element col (8 bf16 = 16B)
    const unsigned short* Ag = A + (size_t)tm * 128 * 256 + (size_t)r0 * 256 + ce;
    const unsigned short* Bg = BT + (size_t)tn * 128 * 256 + (size_t)r0 * 256 + ce;

    const int fr = lane & 15;
    const int ko = (lane >> 4) * 8;

    for (int ks = 0; ks < 8; ++ks) {
        const int k0 = ks * 32;
#pragma unroll
        for (int s = 0; s < 2; ++s) {
            gload16(Ag + (size_t)s * 64 * 256 + k0, (char*)Al + s * 4096 + wave * 1024);
            gload16(Bg + (size_t)s * 64 * 256 + k0, (char*)Bl + s * 4096 + wave * 1024);
        }
        __syncthreads();
        bf16x8 af[4], bfr[4];
#pragma unroll
        for (int i = 0; i < 4; ++i) {
            af[i]  = *(const bf16x8*)&Al[(wm + i * 16 + fr) * 32 + ko];
            bfr[i] = *(const bf16x8*)&Bl[(wn + i * 16 + fr) * 32 + ko];
        }
#pragma unroll
        for (int i = 0; i < 4; ++i)
#pragma unroll
            for (int j = 0; j < 4; ++j)
                acc[i][j] = __builtin_amdgcn_mfma_f32_16x16x32_bf16(af[i], bfr[j], acc[i][j], 0, 0, 0);
        __syncthreads();
    }

    const int colbase = tn * 128 + wn;
    const int rbase = tm * 128 + wm + (lane >> 4) * 4;
#pragma unroll
    for (int i = 0; i < 4; ++i) {
#pragma unroll
        for (int j = 0; j < 4; ++j) {
            const int cg = colbase + j * 16 + (lane & 15);
#pragma unroll
            for (int q = 0; q < 4; ++q) {
                const int rg = rbase + i * 16 + q;
                if (rg < M) {
                    float v = acc[i][j][q];
                    if (cg < 256) {
                        xs[(size_t)rg * 256 + cg] = v;
                    } else if (cg < 512) {
                        float t = v + bh[cg - 256];
                        hb[(size_t)rg * 256 + (cg - 256)] = t > 0.f ? t : 0.f;
                    } else {
                        xlb[(size_t)rg * 256 + (cg - 512)] = v + bl[cg - 512];
                    }
                }
            }
        }
    }
}

// ---------------- a_src/a_dst: per (node, head) 32-length dot ----------------
__global__ __launch_bounds__(256) void k_attn(const float* __restrict__ xs,
                                              const float* __restrict__ att_src,
                                              const float* __restrict__ att_dst,
                                              float* __restrict__ a_src,
                                              float* __restrict__ a_dst, int N) {
    int t = blockIdx.x * 256 + threadIdx.x;
    int n = t >> 3, hh = t & 7;
    if (n >= N) return;
    const float4* xp = (const float4*)(xs + (size_t)n * 256 + hh * 32);
    const float4* sp = (const float4*)(att_src + hh * 32);
    const float4* dp = (const float4*)(att_dst + hh * 32);
    float sa = 0.f, sd = 0.f;
#pragma unroll
    for (int q = 0; q < 8; ++q) {
        float4 v = xp[q], s = sp[q], d = dp[q];
        sa += v.x * s.x + v.y * s.y + v.z * s.z + v.w * s.w;
        sd += v.x * d.x + v.y * d.y + v.z * d.z + v.w * d.w;
    }
    a_src[t] = sa;
    a_dst[t] = sd;
}

// ---------------- CSR build ----------------
__global__ void k_hist(const int* __restrict__ dst, int E, int* __restrict__ deg) {
    for (int e = blockIdx.x * blockDim.x + threadIdx.x; e < E; e += gridDim.x * blockDim.x)
        atomicAdd(&deg[dst[e]], 1);
}

__global__ __launch_bounds__(256) void k_scan1(const int* __restrict__ deg, int* __restrict__ offs,
                                               int* __restrict__ bsum, int Npad) {
    __shared__ int s[256];
    int t = threadIdx.x;
    int i = blockIdx.x * 256 + t;
    int v = (i < Npad) ? deg[i] : 0;
    s[t] = v;
    __syncthreads();
#pragma unroll
    for (int off = 1; off < 256; off <<= 1) {
        int x = (t >= off) ? s[t - off] : 0;
        __syncthreads();
        s[t] += x;
        __syncthreads();
    }
    offs[i] = s[t] - v;  // exclusive within block
    if (t == 255) bsum[blockIdx.x] = s[255];
}

__global__ __launch_bounds__(512) void k_scan2(int* __restrict__ bsum, int nb) {
    __shared__ int s[512];
    int t = threadIdx.x;
    int v = (t < nb) ? bsum[t] : 0;
    s[t] = v;
    __syncthreads();
#pragma unroll
    for (int off = 1; off < 512; off <<= 1) {
        int x = (t >= off) ? s[t - off] : 0;
        __syncthreads();
        s[t] += x;
        __syncthreads();
    }
    if (t < nb) bsum[t] = s[t] - v;  // exclusive
}

__global__ __launch_bounds__(256) void k_scan3(int* __restrict__ offs, const int* __restrict__ bsum,
                                               int* __restrict__ cursor) {
    int i = blockIdx.x * 256 + threadIdx.x;
    int o = offs[i] + bsum[blockIdx.x];
    offs[i] = o;
    cursor[i] = o;
}

__global__ void k_scatter(const int* __restrict__ ei, const float* __restrict__ ea, int E,
                          int* __restrict__ cursor, int* __restrict__ csr_src,
                          float* __restrict__ csr_w) {
    for (int e = blockIdx.x * blockDim.x + threadIdx.x; e < E; e += gridDim.x * blockDim.x) {
        int d = ei[(size_t)E + e];
        int pos = atomicAdd(&cursor[d], 1);
        csr_src[pos] = ei[e];
        csr_w[pos] = ea[e];
    }
}

// ---------------- aggregation + epilogue: one wave per dst node ----------------
__global__ __launch_bounds__(256) void k_agg(
    const int* __restrict__ offs, const int* __restrict__ deg,
    const int* __restrict__ csr_src, const float* __restrict__ csr_w,
    const float* __restrict__ a_src, const float* __restrict__ a_dst,
    const float* __restrict__ xs, const float* __restrict__ hb, const float* __restrict__ xlb,
    const float* __restrict__ x, const float* __restrict__ ln_g, const float* __restrict__ ln_b,
    const float* __restrict__ beta, float* __restrict__ out, int N) {
    const int wave = threadIdx.x >> 6, lane = threadIdx.x & 63;
    const int n = blockIdx.x * 4 + wave;
    if (n >= N) return;
    const int start = offs[n];
    const int end = start + deg[n];
    const int hA = lane & 7;   // head for pass A (8 edges x 8 heads)
    const int hM = lane >> 3;  // head owning this lane's 4 msg columns

    const float adstA = a_dst[n * 8 + hA];

    // pass A: per-head max of leaky_relu(a_src[src]+a_dst[n])
    float m = -INFINITY;
    for (int g = start + (lane >> 3); g < end; g += 8) {
        int s = csr_src[g];
        float e = a_src[s * 8 + hA] + adstA;
        e = (e > 0.f) ? e : 0.2f * e;
        m = fmaxf(m, e);
    }
    m = fmaxf(m, __shfl_xor(m, 8));
    m = fmaxf(m, __shfl_xor(m, 16));
    m = fmaxf(m, __shfl_xor(m, 32));
    // remap head-layout: lane needs head hM values (lane 0..7 hold heads 0..7)
    const float mM = __shfl(m, hM);
    const float adstM = __shfl(adstA, hM);

    // pass B: denom and unnormalized message accumulation
    f32x4 acc = {0.f, 0.f, 0.f, 0.f};
    float denom = 0.f;
    for (int p = start; p < end; ++p) {
        int s = csr_src[p];
        float w = csr_w[p];
        float e = a_src[s * 8 + hM] + adstM;
        e = (e > 0.f) ? e : 0.2f * e;
        float pv = __expf(e - mM) * w;
        denom += pv;
        f32x4 v = *(const f32x4*)(xs + (size_t)s * 256 + lane * 4);
        acc += pv * v;
    }
    const float inv = 1.f / (denom + 1e-16f);

    // epilogue: xg = relu(msg + xl); t = h*xg; LN; beta-mix; +x
    const size_t base = (size_t)n * 256 + lane * 4;
    f32x4 xlv = *(const f32x4*)(xlb + base);
    f32x4 hv = *(const f32x4*)(hb + base);
    f32x4 xg;
    f32x4 t4;
    float s1 = 0.f, s2 = 0.f;
#pragma unroll
    for (int q = 0; q < 4; ++q) {
        float g = acc[q] * inv + xlv[q];
        g = g > 0.f ? g : 0.f;
        xg[q] = g;
        float t = hv[q] * g;
        t4[q] = t;
        s1 += t;
        s2 += t * t;
    }
#pragma unroll
    for (int off = 32; off; off >>= 1) {
        s1 += __shfl_xor(s1, off);
        s2 += __shfl_xor(s2, off);
    }
    const float mu = s1 * (1.f / 256.f);
    const float var = s2 * (1.f / 256.f) - mu * mu;
    const float rs = rsqrtf(var + 1e-5f);

    f32x4 g4 = *(const f32x4*)(ln_g + lane * 4);
    f32x4 b4 = *(const f32x4*)(ln_b + lane * 4);
    f32x4 be = *(const f32x4*)(beta + lane * 4);
    f32x4 xin = *(const f32x4*)(x + base);
    f32x4 o;
#pragma unroll
    for (int q = 0; q < 4; ++q) {
        float ln = (t4[q] - mu) * rs * g4[q] + b4[q];
        o[q] = (1.f - be[q]) * ln + be[q] * xg[q] + xin[q];
    }
    *(f32x4*)(out + base) = o;
}

extern "C" void kernel_launch(void* const* d_in, const int* in_sizes, int n_in,
                              void* d_out, int out_size, void* d_ws, size_t ws_size,
                              hipStream_t stream) {
    const float* x = (const float*)d_in[0];
    const int* ei = (const int*)d_in[1];
    const float* ea = (const float*)d_in[2];
    const float* Wg = (const float*)d_in[3];
    const float* att_src = (const float*)d_in[4];
    const float* att_dst = (const float*)d_in[5];
    const float* Wh = (const float*)d_in[6];
    const float* bh = (const float*)d_in[7];
    const float* Wl = (const float*)d_in[8];
    const float* bl = (const float*)d_in[9];
    const float* ln_g = (const float*)d_in[10];
    const float* ln_b = (const float*)d_in[11];
    const float* beta = (const float*)d_in[12];
    float* out = (float*)d_out;

    const int DH = 256;
    const int N = in_sizes[0] / DH;      // 100000
    const int E = in_sizes[2];           // 1600000
    const int Mpad = ((N + 127) / 128) * 128;   // 100096
    const int Npad = ((N + 255) / 256) * 256;   // 100096
    const int nscanb = Npad / 256;              // 391

    char* w = (char*)d_ws;
    auto take = [&](size_t bytes) -> char* {
        char* p = w;
        w += (bytes + 255) & ~(size_t)255;
        return p;
    };
    float* xs = (float*)take((size_t)N * DH * 4);
    float* hb = (float*)take((size_t)N * DH * 4);
    float* xlb = (float*)take((size_t)N * DH * 4);
    float* a_src = (float*)take((size_t)N * 8 * 4);
    float* a_dst = (float*)take((size_t)N * 8 * 4);
    unsigned short* xbf = (unsigned short*)take((size_t)Mpad * DH * 2);
    unsigned short* wt = (unsigned short*)take((size_t)768 * 256 * 2);
    int* deg = (int*)take((size_t)Npad * 4);
    int* offs = (int*)take((size_t)Npad * 4);
    int* cursor = (int*)take((size_t)Npad * 4);
    int* bsum = (int*)take(512 * 4);
    int* csr_src = (int*)take((size_t)E * 4);
    float* csr_w = (float*)take((size_t)E * 4);

    hipMemsetAsync(deg, 0, (size_t)Npad * 4, stream);

    // bf16 conversions
    k_cvt_x<<<Mpad / 4, 256, 0, stream>>>(x, xbf, (long)N * DH, (long)Mpad * DH);
    k_wt<<<768, 256, 0, stream>>>(Wg, Wh, Wl, wt);

    // CSR build (independent of GEMM)
    k_hist<<<2048, 256, 0, stream>>>(ei + E, E, deg);
    k_scan1<<<nscanb, 256, 0, stream>>>(deg, offs, bsum, Npad);
    k_scan2<<<1, 512, 0, stream>>>(bsum, nscanb);
    k_scan3<<<nscanb, 256, 0, stream>>>(offs, bsum, cursor);
    k_scatter<<<2048, 256, 0, stream>>>(ei, ea, E, cursor, csr_src, csr_w);

    // fused 3-way GEMM
    k_gemm<<<dim3(Mpad / 128, 6), 256, 0, stream>>>(xbf, wt, xs, hb, xlb, bh, bl, N);

    // attention coefficients
    k_attn<<<(N * 8 + 255) / 256, 256, 0, stream>>>(xs, att_src, att_dst, a_src, a_dst, N);

    // aggregation + epilogue
    k_agg<<<(N + 3) / 4, 256, 0, stream>>>(offs, deg, csr_src, csr_w, a_src, a_dst,
                                           xs, hb, xlb, x, ln_g, ln_b, beta, out, N);
}

// Round 2
// 660.842 us; speedup vs baseline: 1.1361x; 1.1361x over previous
//
#include <hip/hip_runtime.h>

typedef __attribute__((ext_vector_type(4))) float f32x4;
typedef __attribute__((ext_vector_type(8))) __bf16 bf16x8;

__device__ __forceinline__ unsigned short f2bf(float f) {
    return __builtin_bit_cast(unsigned short, (__bf16)f);
}
__device__ __forceinline__ float bf2f(unsigned short u) {
    return __builtin_bit_cast(float, (unsigned)u << 16);
}

__device__ __forceinline__ void gload16(const void* g, void* l) {
    __builtin_amdgcn_global_load_lds(
        (const __attribute__((address_space(1))) void*)g,
        (__attribute__((address_space(3))) void*)l, 16, 0, 0);
}

// ---------------- convert x (f32 -> bf16, zero-pad rows to Mpad) ----------------
__global__ __launch_bounds__(256) void k_cvt_x(const float* __restrict__ x,
                                               unsigned short* __restrict__ xb,
                                               long total, long totalPad) {
    long i = ((long)blockIdx.x * 256 + threadIdx.x) * 4;
    if (i >= totalPad) return;
    if (i < total) {  // total is a multiple of 4
        float4 v = *(const float4*)(x + i);
        ushort4 u;
        u.x = f2bf(v.x); u.y = f2bf(v.y); u.z = f2bf(v.z); u.w = f2bf(v.w);
        *(ushort4*)(xb + i) = u;
    } else {
        ushort4 u = {0, 0, 0, 0};
        *(ushort4*)(xb + i) = u;
    }
}

// ---------------- build WT = [Wg|Wh|Wl]^T as bf16, 768 x 256 (n-major) ----------------
__global__ __launch_bounds__(256) void k_wt(const float* __restrict__ Wg,
                                            const float* __restrict__ Wh,
                                            const float* __restrict__ Wl,
                                            unsigned short* __restrict__ wt) {
    int t = blockIdx.x * 256 + threadIdx.x;   // t = nn*256 + k
    int nn = t >> 8, k = t & 255;
    const float* W = (nn < 256) ? Wg : (nn < 512) ? Wh : Wl;
    int c = nn & 255;
    wt[t] = f2bf(W[k * 256 + c]);
}

// ---------------- fused GEMM: C(Mpad x 768) = Xbf16 @ [Wg|Wh|Wl] ----------------
// epilogue (bf16 outputs): cols 0-255 -> xs ; 256-511 -> h=relu(+bh) ; 512-767 -> xl=+bl
__global__ __launch_bounds__(256) void k_gemm(
    const unsigned short* __restrict__ A,   // Mpad x 256 bf16
    const unsigned short* __restrict__ BT,  // 768 x 256 bf16 (row n, col k)
    unsigned short* __restrict__ xs, unsigned short* __restrict__ hb,
    unsigned short* __restrict__ xlb,
    const float* __restrict__ bh, const float* __restrict__ bl, int M) {
    __shared__ unsigned short Al[128 * 32];
    __shared__ unsigned short Bl[128 * 32];
    const int tid = threadIdx.x;
    const int lane = tid & 63;
    const int wave = tid >> 6;
    const int tm = blockIdx.x, tn = blockIdx.y;
    const int wm = (wave >> 1) * 64, wn = (wave & 1) * 64;

    f32x4 acc[4][4] = {};

    const int r0 = tid >> 2;            // row within 64-row sweep
    const int ce = (tid & 3) * 8;       // element col (8 bf16 = 16B)
    const unsigned short* Ag = A + (size_t)tm * 128 * 256 + (size_t)r0 * 256 + ce;
    const unsigned short* Bg = BT + (size_t)tn * 128 * 256 + (size_t)r0 * 256 + ce;

    const int fr = lane & 15;
    const int ko = (lane >> 4) * 8;

    for (int ks = 0; ks < 8; ++ks) {
        const int k0 = ks * 32;
#pragma unroll
        for (int s = 0; s < 2; ++s) {
            gload16(Ag + (size_t)s * 64 * 256 + k0, (char*)Al + s * 4096 + wave * 1024);
            gload16(Bg + (size_t)s * 64 * 256 + k0, (char*)Bl + s * 4096 + wave * 1024);
        }
        __syncthreads();
        bf16x8 af[4], bfr[4];
#pragma unroll
        for (int i = 0; i < 4; ++i) {
            af[i]  = *(const bf16x8*)&Al[(wm + i * 16 + fr) * 32 + ko];
            bfr[i] = *(const bf16x8*)&Bl[(wn + i * 16 + fr) * 32 + ko];
        }
#pragma unroll
        for (int i = 0; i < 4; ++i)
#pragma unroll
            for (int j = 0; j < 4; ++j)
                acc[i][j] = __builtin_amdgcn_mfma_f32_16x16x32_bf16(af[i], bfr[j], acc[i][j], 0, 0, 0);
        __syncthreads();
    }

    const int colbase = tn * 128 + wn;
    const int rbase = tm * 128 + wm + (lane >> 4) * 4;
#pragma unroll
    for (int i = 0; i < 4; ++i) {
#pragma unroll
        for (int j = 0; j < 4; ++j) {
            const int cg = colbase + j * 16 + (lane & 15);
#pragma unroll
            for (int q = 0; q < 4; ++q) {
                const int rg = rbase + i * 16 + q;
                if (rg < M) {
                    float v = acc[i][j][q];
                    if (cg < 256) {
                        xs[(size_t)rg * 256 + cg] = f2bf(v);
                    } else if (cg < 512) {
                        float t = v + bh[cg - 256];
                        hb[(size_t)rg * 256 + (cg - 256)] = f2bf(t > 0.f ? t : 0.f);
                    } else {
                        xlb[(size_t)rg * 256 + (cg - 512)] = f2bf(v + bl[cg - 512]);
                    }
                }
            }
        }
    }
}

// ---------------- a_src/a_dst: per (node, head) 32-length dot (bf16 xs) ----------------
__global__ __launch_bounds__(256) void k_attn(const unsigned short* __restrict__ xs,
                                              const float* __restrict__ att_src,
                                              const float* __restrict__ att_dst,
                                              float* __restrict__ a_src,
                                              float* __restrict__ a_dst, int N) {
    int t = blockIdx.x * 256 + threadIdx.x;
    int n = t >> 3, hh = t & 7;
    if (n >= N) return;
    const ushort4* xp = (const ushort4*)(xs + (size_t)n * 256 + hh * 32);
    const float4* sp = (const float4*)(att_src + hh * 32);
    const float4* dp = (const float4*)(att_dst + hh * 32);
    float sa = 0.f, sd = 0.f;
#pragma unroll
    for (int q = 0; q < 8; ++q) {
        ushort4 u = xp[q];
        float4 s = sp[q], d = dp[q];
        float v0 = bf2f(u.x), v1 = bf2f(u.y), v2 = bf2f(u.z), v3 = bf2f(u.w);
        sa += v0 * s.x + v1 * s.y + v2 * s.z + v3 * s.w;
        sd += v0 * d.x + v1 * d.y + v2 * d.z + v3 * d.w;
    }
    a_src[t] = sa;
    a_dst[t] = sd;
}

// ---------------- CSR build ----------------
__global__ void k_hist(const int* __restrict__ dst, int E, int* __restrict__ deg) {
    for (int e = blockIdx.x * blockDim.x + threadIdx.x; e < E; e += gridDim.x * blockDim.x)
        atomicAdd(&deg[dst[e]], 1);
}

__global__ __launch_bounds__(256) void k_scan1(const int* __restrict__ deg, int* __restrict__ offs,
                                               int* __restrict__ bsum, int Npad) {
    __shared__ int s[256];
    int t = threadIdx.x;
    int i = blockIdx.x * 256 + t;
    int v = (i < Npad) ? deg[i] : 0;
    s[t] = v;
    __syncthreads();
#pragma unroll
    for (int off = 1; off < 256; off <<= 1) {
        int x = (t >= off) ? s[t - off] : 0;
        __syncthreads();
        s[t] += x;
        __syncthreads();
    }
    offs[i] = s[t] - v;  // exclusive within block
    if (t == 255) bsum[blockIdx.x] = s[255];
}

__global__ __launch_bounds__(512) void k_scan2(int* __restrict__ bsum, int nb) {
    __shared__ int s[512];
    int t = threadIdx.x;
    int v = (t < nb) ? bsum[t] : 0;
    s[t] = v;
    __syncthreads();
#pragma unroll
    for (int off = 1; off < 512; off <<= 1) {
        int x = (t >= off) ? s[t - off] : 0;
        __syncthreads();
        s[t] += x;
        __syncthreads();
    }
    if (t < nb) bsum[t] = s[t] - v;  // exclusive
}

__global__ __launch_bounds__(256) void k_scan3(int* __restrict__ offs, const int* __restrict__ bsum,
                                               int* __restrict__ cursor) {
    int i = blockIdx.x * 256 + threadIdx.x;
    int o = offs[i] + bsum[blockIdx.x];
    offs[i] = o;
    cursor[i] = o;
}

__global__ void k_scatter(const int* __restrict__ ei, const float* __restrict__ ea, int E,
                          int* __restrict__ cursor, int* __restrict__ csr_src,
                          float* __restrict__ csr_w) {
    for (int e = blockIdx.x * blockDim.x + threadIdx.x; e < E; e += gridDim.x * blockDim.x) {
        int d = ei[(size_t)E + e];
        int pos = atomicAdd(&cursor[d], 1);
        csr_src[pos] = ei[e];
        csr_w[pos] = ea[e];
    }
}

// ---------------- aggregation + epilogue: one wave per dst node, SINGLE PASS ----------------
// exp without max-subtraction: logits are O(+-4), alpha ratio is identical.
__global__ __launch_bounds__(256) void k_agg(
    const int* __restrict__ offs, const int* __restrict__ deg,
    const int* __restrict__ csr_src, const float* __restrict__ csr_w,
    const float* __restrict__ a_src, const float* __restrict__ a_dst,
    const unsigned short* __restrict__ xs, const unsigned short* __restrict__ hb,
    const unsigned short* __restrict__ xlb,
    const float* __restrict__ x, const float* __restrict__ ln_g, const float* __restrict__ ln_b,
    const float* __restrict__ beta, float* __restrict__ out, int N) {
    const int wave = threadIdx.x >> 6, lane = threadIdx.x & 63;
    const int n = blockIdx.x * 4 + wave;
    if (n >= N) return;
    const int start = offs[n];
    const int end = start + deg[n];
    const int hM = lane >> 3;  // head owning this lane's 4 msg columns
    const float adstM = a_dst[n * 8 + hM];

    f32x4 acc = {0.f, 0.f, 0.f, 0.f};
    float denom = 0.f;
    for (int p = start; p < end; ++p) {
        int s = csr_src[p];
        float w = csr_w[p];
        float e = a_src[s * 8 + hM] + adstM;
        e = (e > 0.f) ? e : 0.2f * e;
        float pv = __expf(e) * w;
        denom += pv;
        ushort4 u = *(const ushort4*)(xs + (size_t)s * 256 + lane * 4);
        acc[0] += pv * bf2f(u.x);
        acc[1] += pv * bf2f(u.y);
        acc[2] += pv * bf2f(u.z);
        acc[3] += pv * bf2f(u.w);
    }
    const float inv = 1.f / (denom + 1e-16f);

    // epilogue: xg = relu(msg + xl); t = h*xg; LN; beta-mix; +x
    const size_t base = (size_t)n * 256 + lane * 4;
    ushort4 xlu = *(const ushort4*)(xlb + base);
    ushort4 hu = *(const ushort4*)(hb + base);
    f32x4 xg;
    f32x4 t4;
    float s1 = 0.f, s2 = 0.f;
    const float xl0[4] = {bf2f(xlu.x), bf2f(xlu.y), bf2f(xlu.z), bf2f(xlu.w)};
    const float hv0[4] = {bf2f(hu.x), bf2f(hu.y), bf2f(hu.z), bf2f(hu.w)};
#pragma unroll
    for (int q = 0; q < 4; ++q) {
        float g = acc[q] * inv + xl0[q];
        g = g > 0.f ? g : 0.f;
        xg[q] = g;
        float t = hv0[q] * g;
        t4[q] = t;
        s1 += t;
        s2 += t * t;
    }
#pragma unroll
    for (int off = 32; off; off >>= 1) {
        s1 += __shfl_xor(s1, off);
        s2 += __shfl_xor(s2, off);
    }
    const float mu = s1 * (1.f / 256.f);
    const float var = s2 * (1.f / 256.f) - mu * mu;
    const float rs = rsqrtf(var + 1e-5f);

    f32x4 g4 = *(const f32x4*)(ln_g + lane * 4);
    f32x4 b4 = *(const f32x4*)(ln_b + lane * 4);
    f32x4 be = *(const f32x4*)(beta + lane * 4);
    f32x4 xin = *(const f32x4*)(x + base);
    f32x4 o;
#pragma unroll
    for (int q = 0; q < 4; ++q) {
        float ln = (t4[q] - mu) * rs * g4[q] + b4[q];
        o[q] = (1.f - be[q]) * ln + be[q] * xg[q] + xin[q];
    }
    *(f32x4*)(out + base) = o;
}

extern "C" void kernel_launch(void* const* d_in, const int* in_sizes, int n_in,
                              void* d_out, int out_size, void* d_ws, size_t ws_size,
                              hipStream_t stream) {
    const float* x = (const float*)d_in[0];
    const int* ei = (const int*)d_in[1];
    const float* ea = (const float*)d_in[2];
    const float* Wg = (const float*)d_in[3];
    const float* att_src = (const float*)d_in[4];
    const float* att_dst = (const float*)d_in[5];
    const float* Wh = (const float*)d_in[6];
    const float* bh = (const float*)d_in[7];
    const float* Wl = (const float*)d_in[8];
    const float* bl = (const float*)d_in[9];
    const float* ln_g = (const float*)d_in[10];
    const float* ln_b = (const float*)d_in[11];
    const float* beta = (const float*)d_in[12];
    float* out = (float*)d_out;

    const int DH = 256;
    const int N = in_sizes[0] / DH;      // 100000
    const int E = in_sizes[2];           // 1600000
    const int Mpad = ((N + 127) / 128) * 128;   // 100096
    const int Npad = ((N + 255) / 256) * 256;   // 100096
    const int nscanb = Npad / 256;              // 391

    char* w = (char*)d_ws;
    auto take = [&](size_t bytes) -> char* {
        char* p = w;
        w += (bytes + 255) & ~(size_t)255;
        return p;
    };
    unsigned short* xs = (unsigned short*)take((size_t)N * DH * 2);
    unsigned short* hb = (unsigned short*)take((size_t)N * DH * 2);
    unsigned short* xlb = (unsigned short*)take((size_t)N * DH * 2);
    float* a_src = (float*)take((size_t)N * 8 * 4);
    float* a_dst = (float*)take((size_t)N * 8 * 4);
    unsigned short* xbf = (unsigned short*)take((size_t)Mpad * DH * 2);
    unsigned short* wt = (unsigned short*)take((size_t)768 * 256 * 2);
    int* deg = (int*)take((size_t)Npad * 4);
    int* offs = (int*)take((size_t)Npad * 4);
    int* cursor = (int*)take((size_t)Npad * 4);
    int* bsum = (int*)take(512 * 4);
    int* csr_src = (int*)take((size_t)E * 4);
    float* csr_w = (float*)take((size_t)E * 4);

    hipMemsetAsync(deg, 0, (size_t)Npad * 4, stream);

    // bf16 conversions
    k_cvt_x<<<Mpad / 4, 256, 0, stream>>>(x, xbf, (long)N * DH, (long)Mpad * DH);
    k_wt<<<768, 256, 0, stream>>>(Wg, Wh, Wl, wt);

    // CSR build
    k_hist<<<2048, 256, 0, stream>>>(ei + E, E, deg);
    k_scan1<<<nscanb, 256, 0, stream>>>(deg, offs, bsum, Npad);
    k_scan2<<<1, 512, 0, stream>>>(bsum, nscanb);
    k_scan3<<<nscanb, 256, 0, stream>>>(offs, bsum, cursor);
    k_scatter<<<2048, 256, 0, stream>>>(ei, ea, E, cursor, csr_src, csr_w);

    // fused 3-way GEMM
    k_gemm<<<dim3(Mpad / 128, 6), 256, 0, stream>>>(xbf, wt, xs, hb, xlb, bh, bl, N);

    // attention coefficients
    k_attn<<<(N * 8 + 255) / 256, 256, 0, stream>>>(xs, att_src, att_dst, a_src, a_dst, N);

    // aggregation + epilogue
    k_agg<<<(N + 3) / 4, 256, 0, stream>>>(offs, deg, csr_src, csr_w, a_src, a_dst,
                                           xs, hb, xlb, x, ln_g, ln_b, beta, out, N);
}

// Round 3
// 585.181 us; speedup vs baseline: 1.2830x; 1.1293x over previous
//
#include <hip/hip_runtime.h>

typedef __attribute__((ext_vector_type(4))) float f32x4;
typedef __attribute__((ext_vector_type(8))) __bf16 bf16x8;

__device__ __forceinline__ unsigned short f2bf(float f) {
    return __builtin_bit_cast(unsigned short, (__bf16)f);
}
__device__ __forceinline__ float bf2f(unsigned short u) {
    return __builtin_bit_cast(float, (unsigned)u << 16);
}

__device__ __forceinline__ void gload16(const void* g, void* l) {
    __builtin_amdgcn_global_load_lds(
        (const __attribute__((address_space(1))) void*)g,
        (__attribute__((address_space(3))) void*)l, 16, 0, 0);
}

// ---------------- convert x (f32 -> bf16, zero-pad rows to Mpad) ----------------
__global__ __launch_bounds__(256) void k_cvt_x(const float* __restrict__ x,
                                               unsigned short* __restrict__ xb,
                                               long total, long totalPad) {
    long i = ((long)blockIdx.x * 256 + threadIdx.x) * 4;
    if (i >= totalPad) return;
    if (i < total) {
        float4 v = *(const float4*)(x + i);
        ushort4 u;
        u.x = f2bf(v.x); u.y = f2bf(v.y); u.z = f2bf(v.z); u.w = f2bf(v.w);
        *(ushort4*)(xb + i) = u;
    } else {
        ushort4 u = {0, 0, 0, 0};
        *(ushort4*)(xb + i) = u;
    }
}

// ---------------- build WT = [Wg|Wh|Wl]^T as bf16, 768 x 256 (n-major) ----------------
__global__ __launch_bounds__(256) void k_wt(const float* __restrict__ Wg,
                                            const float* __restrict__ Wh,
                                            const float* __restrict__ Wl,
                                            unsigned short* __restrict__ wt) {
    int t = blockIdx.x * 256 + threadIdx.x;   // t = nn*256 + k
    int nn = t >> 8, k = t & 255;
    const float* W = (nn < 256) ? Wg : (nn < 512) ? Wh : Wl;
    int c = nn & 255;
    wt[t] = f2bf(W[k * 256 + c]);
}

// ---------------- fused GEMM: C(Mpad x 768) = Xbf16 @ [Wg|Wh|Wl] ----------------
// 1D grid + bijective XCD-chunked swizzle; tn fast-varying so the 6 blocks
// sharing an A-panel run consecutively on one XCD (A L2 reuse).
__global__ __launch_bounds__(256) void k_gemm(
    const unsigned short* __restrict__ A,   // Mpad x 256 bf16
    const unsigned short* __restrict__ BT,  // 768 x 256 bf16 (row n, col k)
    unsigned short* __restrict__ xs, unsigned short* __restrict__ hb,
    unsigned short* __restrict__ xlb,
    const float* __restrict__ bh, const float* __restrict__ bl, int M, int nwg) {
    __shared__ unsigned short Al[128 * 32];
    __shared__ unsigned short Bl[128 * 32];
    const int bid = blockIdx.x;
    const int xcd = bid & 7, idx = bid >> 3;
    const int q = nwg >> 3, r = nwg & 7;
    const int wg = (xcd < r ? xcd * (q + 1) : r * (q + 1) + (xcd - r) * q) + idx;
    const int tm = wg / 6, tn = wg % 6;

    const int tid = threadIdx.x;
    const int lane = tid & 63;
    const int wave = tid >> 6;
    const int wm = (wave >> 1) * 64, wn = (wave & 1) * 64;

    f32x4 acc[4][4] = {};

    const int r0 = tid >> 2;
    const int ce = (tid & 3) * 8;
    const unsigned short* Ag = A + (size_t)tm * 128 * 256 + (size_t)r0 * 256 + ce;
    const unsigned short* Bg = BT + (size_t)tn * 128 * 256 + (size_t)r0 * 256 + ce;

    const int fr = lane & 15;
    const int ko = (lane >> 4) * 8;

    for (int ks = 0; ks < 8; ++ks) {
        const int k0 = ks * 32;
#pragma unroll
        for (int s = 0; s < 2; ++s) {
            gload16(Ag + (size_t)s * 64 * 256 + k0, (char*)Al + s * 4096 + wave * 1024);
            gload16(Bg + (size_t)s * 64 * 256 + k0, (char*)Bl + s * 4096 + wave * 1024);
        }
        __syncthreads();
        bf16x8 af[4], bfr[4];
#pragma unroll
        for (int i = 0; i < 4; ++i) {
            af[i]  = *(const bf16x8*)&Al[(wm + i * 16 + fr) * 32 + ko];
            bfr[i] = *(const bf16x8*)&Bl[(wn + i * 16 + fr) * 32 + ko];
        }
#pragma unroll
        for (int i = 0; i < 4; ++i)
#pragma unroll
            for (int j = 0; j < 4; ++j)
                acc[i][j] = __builtin_amdgcn_mfma_f32_16x16x32_bf16(af[i], bfr[j], acc[i][j], 0, 0, 0);
        __syncthreads();
    }

    const int colbase = tn * 128 + wn;
    const int rbase = tm * 128 + wm + (lane >> 4) * 4;
#pragma unroll
    for (int i = 0; i < 4; ++i) {
#pragma unroll
        for (int j = 0; j < 4; ++j) {
            const int cg = colbase + j * 16 + (lane & 15);
#pragma unroll
            for (int q2 = 0; q2 < 4; ++q2) {
                const int rg = rbase + i * 16 + q2;
                if (rg < M) {
                    float v = acc[i][j][q2];
                    if (cg < 256) {
                        xs[(size_t)rg * 256 + cg] = f2bf(v);
                    } else if (cg < 512) {
                        float t = v + bh[cg - 256];
                        hb[(size_t)rg * 256 + (cg - 256)] = f2bf(t > 0.f ? t : 0.f);
                    } else {
                        xlb[(size_t)rg * 256 + (cg - 512)] = f2bf(v + bl[cg - 512]);
                    }
                }
            }
        }
    }
}

// ---------------- a_src/a_dst: per (node, head) 32-length dot (bf16 xs) ----------------
__global__ __launch_bounds__(256) void k_attn(const unsigned short* __restrict__ xs,
                                              const float* __restrict__ att_src,
                                              const float* __restrict__ att_dst,
                                              float* __restrict__ a_src,
                                              float* __restrict__ a_dst, int N) {
    int t = blockIdx.x * 256 + threadIdx.x;
    int n = t >> 3, hh = t & 7;
    if (n >= N) return;
    const ushort4* xp = (const ushort4*)(xs + (size_t)n * 256 + hh * 32);
    const float4* sp = (const float4*)(att_src + hh * 32);
    const float4* dp = (const float4*)(att_dst + hh * 32);
    float sa = 0.f, sd = 0.f;
#pragma unroll
    for (int q = 0; q < 8; ++q) {
        ushort4 u = xp[q];
        float4 s = sp[q], d = dp[q];
        float v0 = bf2f(u.x), v1 = bf2f(u.y), v2 = bf2f(u.z), v3 = bf2f(u.w);
        sa += v0 * s.x + v1 * s.y + v2 * s.z + v3 * s.w;
        sd += v0 * d.x + v1 * d.y + v2 * d.z + v3 * d.w;
    }
    a_src[t] = sa;
    a_dst[t] = sd;
}

// ---------------- CSR build ----------------
__global__ void k_hist(const int* __restrict__ dst, int E, int* __restrict__ deg) {
    for (int e = blockIdx.x * blockDim.x + threadIdx.x; e < E; e += gridDim.x * blockDim.x)
        atomicAdd(&deg[dst[e]], 1);
}

__global__ __launch_bounds__(256) void k_scan1(const int* __restrict__ deg, int* __restrict__ offs,
                                               int* __restrict__ bsum, int Npad) {
    __shared__ int s[256];
    int t = threadIdx.x;
    int i = blockIdx.x * 256 + t;
    int v = (i < Npad) ? deg[i] : 0;
    s[t] = v;
    __syncthreads();
#pragma unroll
    for (int off = 1; off < 256; off <<= 1) {
        int x = (t >= off) ? s[t - off] : 0;
        __syncthreads();
        s[t] += x;
        __syncthreads();
    }
    offs[i] = s[t] - v;
    if (t == 255) bsum[blockIdx.x] = s[255];
}

__global__ __launch_bounds__(512) void k_scan2(int* __restrict__ bsum, int nb) {
    __shared__ int s[512];
    int t = threadIdx.x;
    int v = (t < nb) ? bsum[t] : 0;
    s[t] = v;
    __syncthreads();
#pragma unroll
    for (int off = 1; off < 512; off <<= 1) {
        int x = (t >= off) ? s[t - off] : 0;
        __syncthreads();
        s[t] += x;
        __syncthreads();
    }
    if (t < nb) bsum[t] = s[t] - v;
}

__global__ __launch_bounds__(256) void k_scan3(int* __restrict__ offs, const int* __restrict__ bsum,
                                               int* __restrict__ cursor) {
    int i = blockIdx.x * 256 + threadIdx.x;
    int o = offs[i] + bsum[blockIdx.x];
    offs[i] = o;
    cursor[i] = o;
}

__global__ void k_scatter(const int* __restrict__ ei, const float* __restrict__ ea, int E,
                          int* __restrict__ cursor, int2* __restrict__ csr) {
    for (int e = blockIdx.x * blockDim.x + threadIdx.x; e < E; e += gridDim.x * blockDim.x) {
        int d = ei[(size_t)E + e];
        int pos = atomicAdd(&cursor[d], 1);
        int2 sw;
        sw.x = ei[e];
        sw.y = __builtin_bit_cast(int, ea[e]);
        csr[pos] = sw;
    }
}

// ---------------- aggregation + epilogue: one wave per dst node ----------------
// 8-edge groups: lanes (head=lane>>3, e=lane&7) compute 64 logits in parallel;
// then 8 wave-uniform row gathers (8-deep MLP) + bpermute pv broadcast.
__global__ __launch_bounds__(256) void k_agg(
    const int* __restrict__ offs, const int* __restrict__ deg,
    const int2* __restrict__ csr,
    const float* __restrict__ a_src, const float* __restrict__ a_dst,
    const unsigned short* __restrict__ xs, const unsigned short* __restrict__ hb,
    const unsigned short* __restrict__ xlb,
    const float* __restrict__ x, const float* __restrict__ ln_g, const float* __restrict__ ln_b,
    const float* __restrict__ beta, float* __restrict__ out, int N) {
    const int wave = threadIdx.x >> 6, lane = threadIdx.x & 63;
    const int n = blockIdx.x * 4 + wave;
    if (n >= N) return;
    const int start = offs[n];
    const int dcount = deg[n];
    const int head = lane >> 3;   // phase-1 logit head AND this lane's msg head
    const int eSub = lane & 7;
    const float adst = a_dst[n * 8 + head];

    f32x4 acc = {0.f, 0.f, 0.f, 0.f};
    float dsum = 0.f;
    const unsigned short* xrow = xs + (size_t)lane * 4;

    for (int g = 0; g < dcount; g += 8) {
        const int eIdx = g + eSub;
        int src = 0;
        float w = 0.f;
        if (eIdx < dcount) {
            int2 sw = csr[start + eIdx];
            src = sw.x;
            w = __builtin_bit_cast(float, sw.y);
        }
        float a = a_src[src * 8 + head] + adst;
        a = (a > 0.f) ? a : 0.2f * a;
        const float pv = __expf(a) * w;   // 0 for masked edges
        dsum += pv;

        ushort4 rows[8];
#pragma unroll
        for (int e = 0; e < 8; ++e) {
            const int s = __shfl(src, e);          // wave-uniform -> SGPR base
            rows[e] = *(const ushort4*)(xrow + (size_t)s * 256);
        }
#pragma unroll
        for (int e = 0; e < 8; ++e) {
            const float p = __shfl(pv, (lane & 56) + e);
            acc[0] += p * bf2f(rows[e].x);
            acc[1] += p * bf2f(rows[e].y);
            acc[2] += p * bf2f(rows[e].z);
            acc[3] += p * bf2f(rows[e].w);
        }
    }
    // reduce denom over the 8 edge-lanes within each head octet
    dsum += __shfl_xor(dsum, 1);
    dsum += __shfl_xor(dsum, 2);
    dsum += __shfl_xor(dsum, 4);
    const float inv = 1.f / (dsum + 1e-16f);

    // epilogue: xg = relu(msg + xl); t = h*xg; LN; beta-mix; +x
    const size_t base = (size_t)n * 256 + lane * 4;
    ushort4 xlu = *(const ushort4*)(xlb + base);
    ushort4 hu = *(const ushort4*)(hb + base);
    f32x4 xg, t4;
    float s1 = 0.f, s2 = 0.f;
    const float xl0[4] = {bf2f(xlu.x), bf2f(xlu.y), bf2f(xlu.z), bf2f(xlu.w)};
    const float hv0[4] = {bf2f(hu.x), bf2f(hu.y), bf2f(hu.z), bf2f(hu.w)};
#pragma unroll
    for (int q = 0; q < 4; ++q) {
        float gg = acc[q] * inv + xl0[q];
        gg = gg > 0.f ? gg : 0.f;
        xg[q] = gg;
        float t = hv0[q] * gg;
        t4[q] = t;
        s1 += t;
        s2 += t * t;
    }
#pragma unroll
    for (int off = 32; off; off >>= 1) {
        s1 += __shfl_xor(s1, off);
        s2 += __shfl_xor(s2, off);
    }
    const float mu = s1 * (1.f / 256.f);
    const float var = s2 * (1.f / 256.f) - mu * mu;
    const float rs = rsqrtf(var + 1e-5f);

    f32x4 g4 = *(const f32x4*)(ln_g + lane * 4);
    f32x4 b4 = *(const f32x4*)(ln_b + lane * 4);
    f32x4 be = *(const f32x4*)(beta + lane * 4);
    f32x4 xin = *(const f32x4*)(x + base);
    f32x4 o;
#pragma unroll
    for (int q = 0; q < 4; ++q) {
        float ln = (t4[q] - mu) * rs * g4[q] + b4[q];
        o[q] = (1.f - be[q]) * ln + be[q] * xg[q] + xin[q];
    }
    *(f32x4*)(out + base) = o;
}

extern "C" void kernel_launch(void* const* d_in, const int* in_sizes, int n_in,
                              void* d_out, int out_size, void* d_ws, size_t ws_size,
                              hipStream_t stream) {
    const float* x = (const float*)d_in[0];
    const int* ei = (const int*)d_in[1];
    const float* ea = (const float*)d_in[2];
    const float* Wg = (const float*)d_in[3];
    const float* att_src = (const float*)d_in[4];
    const float* att_dst = (const float*)d_in[5];
    const float* Wh = (const float*)d_in[6];
    const float* bh = (const float*)d_in[7];
    const float* Wl = (const float*)d_in[8];
    const float* bl = (const float*)d_in[9];
    const float* ln_g = (const float*)d_in[10];
    const float* ln_b = (const float*)d_in[11];
    const float* beta = (const float*)d_in[12];
    float* out = (float*)d_out;

    const int DH = 256;
    const int N = in_sizes[0] / DH;      // 100000
    const int E = in_sizes[2];           // 1600000
    const int Mpad = ((N + 127) / 128) * 128;   // 100096
    const int Npad = ((N + 255) / 256) * 256;   // 100096
    const int nscanb = Npad / 256;              // 391
    const int nwg = (Mpad / 128) * 6;           // 4692

    char* w = (char*)d_ws;
    auto take = [&](size_t bytes) -> char* {
        char* p = w;
        w += (bytes + 255) & ~(size_t)255;
        return p;
    };
    unsigned short* xs = (unsigned short*)take((size_t)N * DH * 2);
    unsigned short* hb = (unsigned short*)take((size_t)N * DH * 2);
    unsigned short* xlb = (unsigned short*)take((size_t)N * DH * 2);
    float* a_src = (float*)take((size_t)N * 8 * 4);
    float* a_dst = (float*)take((size_t)N * 8 * 4);
    unsigned short* xbf = (unsigned short*)take((size_t)Mpad * DH * 2);
    unsigned short* wt = (unsigned short*)take((size_t)768 * 256 * 2);
    int* deg = (int*)take((size_t)Npad * 4);
    int* offs = (int*)take((size_t)Npad * 4);
    int* cursor = (int*)take((size_t)Npad * 4);
    int* bsum = (int*)take(512 * 4);
    int2* csr = (int2*)take((size_t)E * 8);

    hipMemsetAsync(deg, 0, (size_t)Npad * 4, stream);

    // bf16 conversions
    k_cvt_x<<<Mpad / 4, 256, 0, stream>>>(x, xbf, (long)N * DH, (long)Mpad * DH);
    k_wt<<<768, 256, 0, stream>>>(Wg, Wh, Wl, wt);

    // CSR build
    k_hist<<<2048, 256, 0, stream>>>(ei + E, E, deg);
    k_scan1<<<nscanb, 256, 0, stream>>>(deg, offs, bsum, Npad);
    k_scan2<<<1, 512, 0, stream>>>(bsum, nscanb);
    k_scan3<<<nscanb, 256, 0, stream>>>(offs, bsum, cursor);
    k_scatter<<<2048, 256, 0, stream>>>(ei, ea, E, cursor, csr);

    // fused 3-way GEMM (XCD-swizzled 1D grid)
    k_gemm<<<nwg, 256, 0, stream>>>(xbf, wt, xs, hb, xlb, bh, bl, N, nwg);

    // attention coefficients
    k_attn<<<(N * 8 + 255) / 256, 256, 0, stream>>>(xs, att_src, att_dst, a_src, a_dst, N);

    // aggregation + epilogue
    k_agg<<<(N + 3) / 4, 256, 0, stream>>>(offs, deg, csr, a_src, a_dst,
                                           xs, hb, xlb, x, ln_g, ln_b, beta, out, N);
}

// Round 4
// 561.948 us; speedup vs baseline: 1.3361x; 1.0413x over previous
//
#include <hip/hip_runtime.h>

typedef __attribute__((ext_vector_type(4))) float f32x4;
typedef __attribute__((ext_vector_type(8))) __bf16 bf16x8;

__device__ __forceinline__ unsigned short f2bf(float f) {
    return __builtin_bit_cast(unsigned short, (__bf16)f);
}
__device__ __forceinline__ float bf2f(unsigned short u) {
    return __builtin_bit_cast(float, (unsigned)u << 16);
}

__device__ __forceinline__ void gload16(const void* g, void* l) {
    __builtin_amdgcn_global_load_lds(
        (const __attribute__((address_space(1))) void*)g,
        (__attribute__((address_space(3))) void*)l, 16, 0, 0);
}

// ---------------- fused prep: cvt x->bf16 | build WT | degree histogram ----------------
__global__ __launch_bounds__(256) void k_prep(
    const float* __restrict__ x, unsigned short* __restrict__ xb, long total, long totalPad,
    const float* __restrict__ Wg, const float* __restrict__ Wh, const float* __restrict__ Wl,
    unsigned short* __restrict__ wt,
    const int* __restrict__ dst, int E, int* __restrict__ deg,
    int nCvt, int nHist) {
    const int b = blockIdx.x;
    const int tid = threadIdx.x;
    if (b < nCvt) {
        long i = ((long)b * 256 + tid) * 4;
        if (i >= totalPad) return;
        if (i < total) {
            float4 v = *(const float4*)(x + i);
            ushort4 u;
            u.x = f2bf(v.x); u.y = f2bf(v.y); u.z = f2bf(v.z); u.w = f2bf(v.w);
            *(ushort4*)(xb + i) = u;
        } else {
            ushort4 u = {0, 0, 0, 0};
            *(ushort4*)(xb + i) = u;
        }
    } else if (b < nCvt + 768) {
        int t = (b - nCvt) * 256 + tid;   // t = nn*256 + k
        int nn = t >> 8, k = t & 255;
        const float* W = (nn < 256) ? Wg : (nn < 512) ? Wh : Wl;
        wt[t] = f2bf(W[k * 256 + (nn & 255)]);
    } else {
        int bb = b - nCvt - 768;
        for (int e = bb * 256 + tid; e < E; e += nHist * 256)
            atomicAdd(&deg[dst[e]], 1);
    }
}

// ---------------- fused GEMM: C(Mpad x 768) = Xbf16 @ [Wg|Wh|Wl] ----------------
__global__ __launch_bounds__(256) void k_gemm(
    const unsigned short* __restrict__ A,   // Mpad x 256 bf16
    const unsigned short* __restrict__ BT,  // 768 x 256 bf16 (row n, col k)
    unsigned short* __restrict__ xs, unsigned short* __restrict__ hb,
    unsigned short* __restrict__ xlb,
    const float* __restrict__ bh, const float* __restrict__ bl, int M, int nwg) {
    __shared__ unsigned short Al[128 * 32];
    __shared__ unsigned short Bl[128 * 32];
    const int bid = blockIdx.x;
    const int xcd = bid & 7, idx = bid >> 3;
    const int q = nwg >> 3, r = nwg & 7;
    const int wg = (xcd < r ? xcd * (q + 1) : r * (q + 1) + (xcd - r) * q) + idx;
    const int tm = wg / 6, tn = wg % 6;

    const int tid = threadIdx.x;
    const int lane = tid & 63;
    const int wave = tid >> 6;
    const int wm = (wave >> 1) * 64, wn = (wave & 1) * 64;

    f32x4 acc[4][4] = {};

    const int r0 = tid >> 2;
    const int ce = (tid & 3) * 8;
    const unsigned short* Ag = A + (size_t)tm * 128 * 256 + (size_t)r0 * 256 + ce;
    const unsigned short* Bg = BT + (size_t)tn * 128 * 256 + (size_t)r0 * 256 + ce;

    const int fr = lane & 15;
    const int ko = (lane >> 4) * 8;

    for (int ks = 0; ks < 8; ++ks) {
        const int k0 = ks * 32;
#pragma unroll
        for (int s = 0; s < 2; ++s) {
            gload16(Ag + (size_t)s * 64 * 256 + k0, (char*)Al + s * 4096 + wave * 1024);
            gload16(Bg + (size_t)s * 64 * 256 + k0, (char*)Bl + s * 4096 + wave * 1024);
        }
        __syncthreads();
        bf16x8 af[4], bfr[4];
#pragma unroll
        for (int i = 0; i < 4; ++i) {
            af[i]  = *(const bf16x8*)&Al[(wm + i * 16 + fr) * 32 + ko];
            bfr[i] = *(const bf16x8*)&Bl[(wn + i * 16 + fr) * 32 + ko];
        }
#pragma unroll
        for (int i = 0; i < 4; ++i)
#pragma unroll
            for (int j = 0; j < 4; ++j)
                acc[i][j] = __builtin_amdgcn_mfma_f32_16x16x32_bf16(af[i], bfr[j], acc[i][j], 0, 0, 0);
        __syncthreads();
    }

    const int colbase = tn * 128 + wn;
    const int rbase = tm * 128 + wm + (lane >> 4) * 4;
#pragma unroll
    for (int i = 0; i < 4; ++i) {
#pragma unroll
        for (int j = 0; j < 4; ++j) {
            const int cg = colbase + j * 16 + (lane & 15);
#pragma unroll
            for (int q2 = 0; q2 < 4; ++q2) {
                const int rg = rbase + i * 16 + q2;
                if (rg < M) {
                    float v = acc[i][j][q2];
                    if (cg < 256) {
                        xs[(size_t)rg * 256 + cg] = f2bf(v);
                    } else if (cg < 512) {
                        float t = v + bh[cg - 256];
                        hb[(size_t)rg * 256 + (cg - 256)] = f2bf(t > 0.f ? t : 0.f);
                    } else {
                        xlb[(size_t)rg * 256 + (cg - 512)] = f2bf(v + bl[cg - 512]);
                    }
                }
            }
        }
    }
}

// ---------------- a_src/a_dst: per (node, head) 32-length dot (bf16 xs) ----------------
__global__ __launch_bounds__(256) void k_attn(const unsigned short* __restrict__ xs,
                                              const float* __restrict__ att_src,
                                              const float* __restrict__ att_dst,
                                              float* __restrict__ a_src,
                                              float* __restrict__ a_dst, int N) {
    int t = blockIdx.x * 256 + threadIdx.x;
    int n = t >> 3, hh = t & 7;
    if (n >= N) return;
    const ushort4* xp = (const ushort4*)(xs + (size_t)n * 256 + hh * 32);
    const float4* sp = (const float4*)(att_src + hh * 32);
    const float4* dp = (const float4*)(att_dst + hh * 32);
    float sa = 0.f, sd = 0.f;
#pragma unroll
    for (int q = 0; q < 8; ++q) {
        ushort4 u = xp[q];
        float4 s = sp[q], d = dp[q];
        float v0 = bf2f(u.x), v1 = bf2f(u.y), v2 = bf2f(u.z), v3 = bf2f(u.w);
        sa += v0 * s.x + v1 * s.y + v2 * s.z + v3 * s.w;
        sd += v0 * d.x + v1 * d.y + v2 * d.z + v3 * d.w;
    }
    a_src[t] = sa;
    a_dst[t] = sd;
}

// ---------------- scans ----------------
__global__ __launch_bounds__(256) void k_scan1(const int* __restrict__ deg, int* __restrict__ offs,
                                               int* __restrict__ bsum, int Npad) {
    __shared__ int s[256];
    int t = threadIdx.x;
    int i = blockIdx.x * 256 + t;
    int v = (i < Npad) ? deg[i] : 0;
    s[t] = v;
    __syncthreads();
#pragma unroll
    for (int off = 1; off < 256; off <<= 1) {
        int x = (t >= off) ? s[t - off] : 0;
        __syncthreads();
        s[t] += x;
        __syncthreads();
    }
    offs[i] = s[t] - v;
    if (t == 255) bsum[blockIdx.x] = s[255];
}

__global__ __launch_bounds__(512) void k_scan2(int* __restrict__ bsum, int nb) {
    __shared__ int s[512];
    int t = threadIdx.x;
    int v = (t < nb) ? bsum[t] : 0;
    s[t] = v;
    __syncthreads();
#pragma unroll
    for (int off = 1; off < 512; off <<= 1) {
        int x = (t >= off) ? s[t - off] : 0;
        __syncthreads();
        s[t] += x;
        __syncthreads();
    }
    if (t < nb) bsum[t] = s[t] - v;
}

__global__ __launch_bounds__(256) void k_scan3(int* __restrict__ offs, const int* __restrict__ bsum,
                                               int* __restrict__ cursor) {
    int i = blockIdx.x * 256 + threadIdx.x;
    int o = offs[i] + bsum[blockIdx.x];
    offs[i] = o;
    cursor[i] = o;
}

// ---------------- edge pass: CSR scatter + per-(edge,head) pv = exp(leaky(logit))*w ----------------
__global__ void k_edge(const int* __restrict__ ei, const float* __restrict__ ea, int E,
                       const float* __restrict__ a_src, const float* __restrict__ a_dst,
                       int* __restrict__ cursor, int* __restrict__ srcArr,
                       unsigned short* __restrict__ pvArr) {
    for (int e = blockIdx.x * blockDim.x + threadIdx.x; e < E; e += gridDim.x * blockDim.x) {
        const int s = ei[e];
        const int d = ei[(size_t)E + e];
        const float w = ea[e];
        const int pos = atomicAdd(&cursor[d], 1);
        const float4* As = (const float4*)(a_src + (size_t)s * 8);
        const float4* Ad = (const float4*)(a_dst + (size_t)d * 8);
        float4 s0 = As[0], s1 = As[1], d0 = Ad[0], d1 = Ad[1];
        float a[8] = {s0.x + d0.x, s0.y + d0.y, s0.z + d0.z, s0.w + d0.w,
                      s1.x + d1.x, s1.y + d1.y, s1.z + d1.z, s1.w + d1.w};
        unsigned pk[4];
#pragma unroll
        for (int h = 0; h < 4; ++h) {
            float lo = a[2 * h], hi = a[2 * h + 1];
            lo = (lo > 0.f) ? lo : 0.2f * lo;
            hi = (hi > 0.f) ? hi : 0.2f * hi;
            unsigned short plo = f2bf(__expf(lo) * w);
            unsigned short phi = f2bf(__expf(hi) * w);
            pk[h] = (unsigned)plo | ((unsigned)phi << 16);
        }
        srcArr[pos] = s;
        uint4 v = {pk[0], pk[1], pk[2], pk[3]};
        *(uint4*)(pvArr + (size_t)pos * 8) = v;
    }
}

// ---------------- aggregation + epilogue: one wave per dst node ----------------
// inner loop: coalesced src+pv loads, 8 wave-uniform row gathers, fma. No exp, no a_src gather.
__global__ __launch_bounds__(256) void k_agg(
    const int* __restrict__ offs, const int* __restrict__ deg,
    const int* __restrict__ srcArr, const unsigned short* __restrict__ pvArr,
    const unsigned short* __restrict__ xs, const unsigned short* __restrict__ hb,
    const unsigned short* __restrict__ xlb,
    const float* __restrict__ x, const float* __restrict__ ln_g, const float* __restrict__ ln_b,
    const float* __restrict__ beta, float* __restrict__ out, int N) {
    const int wave = threadIdx.x >> 6, lane = threadIdx.x & 63;
    const int n = blockIdx.x * 4 + wave;
    if (n >= N) return;
    const int start = offs[n];
    const int dcount = deg[n];
    const int head = lane >> 3;   // this lane's msg head (cols lane*4..lane*4+3)
    const int eSub = lane & 7;

    f32x4 acc = {0.f, 0.f, 0.f, 0.f};
    float dsum = 0.f;
    const unsigned short* xrow = xs + (size_t)lane * 4;

    for (int g = 0; g < dcount; g += 8) {
        const int eIdx = g + eSub;
        const bool act = eIdx < dcount;
        int src = 0;
        float pv = 0.f;
        if (act) {
            src = srcArr[start + eIdx];
            pv = bf2f(pvArr[(size_t)(start + eIdx) * 8 + head]);
        }
        dsum += pv;

        ushort4 rows[8];
#pragma unroll
        for (int e = 0; e < 8; ++e) {
            const int s = __shfl(src, e);          // wave-uniform -> SGPR base
            rows[e] = *(const ushort4*)(xrow + (size_t)s * 256);
        }
#pragma unroll
        for (int e = 0; e < 8; ++e) {
            const float p = __shfl(pv, (lane & 56) + e);
            acc[0] += p * bf2f(rows[e].x);
            acc[1] += p * bf2f(rows[e].y);
            acc[2] += p * bf2f(rows[e].z);
            acc[3] += p * bf2f(rows[e].w);
        }
    }
    // reduce denom over the 8 edge-lanes within each head octet
    dsum += __shfl_xor(dsum, 1);
    dsum += __shfl_xor(dsum, 2);
    dsum += __shfl_xor(dsum, 4);
    const float inv = 1.f / (dsum + 1e-16f);

    // epilogue: xg = relu(msg + xl); t = h*xg; LN; beta-mix; +x
    const size_t base = (size_t)n * 256 + lane * 4;
    ushort4 xlu = *(const ushort4*)(xlb + base);
    ushort4 hu = *(const ushort4*)(hb + base);
    f32x4 xg, t4;
    float s1 = 0.f, s2 = 0.f;
    const float xl0[4] = {bf2f(xlu.x), bf2f(xlu.y), bf2f(xlu.z), bf2f(xlu.w)};
    const float hv0[4] = {bf2f(hu.x), bf2f(hu.y), bf2f(hu.z), bf2f(hu.w)};
#pragma unroll
    for (int q = 0; q < 4; ++q) {
        float gg = acc[q] * inv + xl0[q];
        gg = gg > 0.f ? gg : 0.f;
        xg[q] = gg;
        float t = hv0[q] * gg;
        t4[q] = t;
        s1 += t;
        s2 += t * t;
    }
#pragma unroll
    for (int off = 32; off; off >>= 1) {
        s1 += __shfl_xor(s1, off);
        s2 += __shfl_xor(s2, off);
    }
    const float mu = s1 * (1.f / 256.f);
    const float var = s2 * (1.f / 256.f) - mu * mu;
    const float rs = rsqrtf(var + 1e-5f);

    f32x4 g4 = *(const f32x4*)(ln_g + lane * 4);
    f32x4 b4 = *(const f32x4*)(ln_b + lane * 4);
    f32x4 be = *(const f32x4*)(beta + lane * 4);
    f32x4 xin = *(const f32x4*)(x + base);
    f32x4 o;
#pragma unroll
    for (int q = 0; q < 4; ++q) {
        float ln = (t4[q] - mu) * rs * g4[q] + b4[q];
        o[q] = (1.f - be[q]) * ln + be[q] * xg[q] + xin[q];
    }
    *(f32x4*)(out + base) = o;
}

extern "C" void kernel_launch(void* const* d_in, const int* in_sizes, int n_in,
                              void* d_out, int out_size, void* d_ws, size_t ws_size,
                              hipStream_t stream) {
    const float* x = (const float*)d_in[0];
    const int* ei = (const int*)d_in[1];
    const float* ea = (const float*)d_in[2];
    const float* Wg = (const float*)d_in[3];
    const float* att_src = (const float*)d_in[4];
    const float* att_dst = (const float*)d_in[5];
    const float* Wh = (const float*)d_in[6];
    const float* bh = (const float*)d_in[7];
    const float* Wl = (const float*)d_in[8];
    const float* bl = (const float*)d_in[9];
    const float* ln_g = (const float*)d_in[10];
    const float* ln_b = (const float*)d_in[11];
    const float* beta = (const float*)d_in[12];
    float* out = (float*)d_out;

    const int DH = 256;
    const int N = in_sizes[0] / DH;      // 100000
    const int E = in_sizes[2];           // 1600000
    const int Mpad = ((N + 127) / 128) * 128;   // 100096
    const int Npad = ((N + 255) / 256) * 256;   // 100096
    const int nscanb = Npad / 256;              // 391
    const int nwg = (Mpad / 128) * 6;           // 4692
    const int nCvt = Mpad / 4;                  // 25024
    const int nHist = 2048;

    char* w = (char*)d_ws;
    auto take = [&](size_t bytes) -> char* {
        char* p = w;
        w += (bytes + 255) & ~(size_t)255;
        return p;
    };
    unsigned short* xs = (unsigned short*)take((size_t)N * DH * 2);
    unsigned short* hb = (unsigned short*)take((size_t)N * DH * 2);
    unsigned short* xlb = (unsigned short*)take((size_t)N * DH * 2);
    float* a_src = (float*)take((size_t)N * 8 * 4);
    float* a_dst = (float*)take((size_t)N * 8 * 4);
    unsigned short* xbf = (unsigned short*)take((size_t)Mpad * DH * 2);
    unsigned short* wt = (unsigned short*)take((size_t)768 * 256 * 2);
    int* deg = (int*)take((size_t)Npad * 4);
    int* offs = (int*)take((size_t)Npad * 4);
    int* cursor = (int*)take((size_t)Npad * 4);
    int* bsum = (int*)take(512 * 4);
    int* srcArr = (int*)take((size_t)E * 4);
    unsigned short* pvArr = (unsigned short*)take((size_t)E * 8 * 2);

    hipMemsetAsync(deg, 0, (size_t)Npad * 4, stream);

    // fused prep: cvt + wt + hist
    k_prep<<<nCvt + 768 + nHist, 256, 0, stream>>>(x, xbf, (long)N * DH, (long)Mpad * DH,
                                                   Wg, Wh, Wl, wt, ei + E, E, deg, nCvt, nHist);

    // offsets
    k_scan1<<<nscanb, 256, 0, stream>>>(deg, offs, bsum, Npad);
    k_scan2<<<1, 512, 0, stream>>>(bsum, nscanb);
    k_scan3<<<nscanb, 256, 0, stream>>>(offs, bsum, cursor);

    // fused 3-way GEMM (XCD-swizzled 1D grid)
    k_gemm<<<nwg, 256, 0, stream>>>(xbf, wt, xs, hb, xlb, bh, bl, N, nwg);

    // attention coefficients
    k_attn<<<(N * 8 + 255) / 256, 256, 0, stream>>>(xs, att_src, att_dst, a_src, a_dst, N);

    // edge pass: scatter + pv precompute
    k_edge<<<2048, 256, 0, stream>>>(ei, ea, E, a_src, a_dst, cursor, srcArr, pvArr);

    // aggregation + epilogue
    k_agg<<<(N + 3) / 4, 256, 0, stream>>>(offs, deg, srcArr, pvArr,
                                           xs, hb, xlb, x, ln_g, ln_b, beta, out, N);
}